// Round 6
// baseline (156.831 us; speedup 1.0000x reference)
//
#include <hip/hip_runtime.h>

#define H_ 448
#define W_ 96
#define CIN_ 128
#define HW_ (H_*W_)   // 43008
#define PPB 48        // pixels per block (half line)

__device__ __forceinline__ float lrelu(float v){ return v > 0.0f ? v : 0.01f*v; }

// Counting sort of PPB pixels by class (NC classes). All threads must call.
template<int NC>
__device__ __forceinline__ void sort_by_class(const unsigned char* s_cls, short* s_perm,
                                              int* s_cnt, int* s_off, int t)
{
    if (t < NC){
        int c = 0;
        for (int p = 0; p < PPB; p++) if (s_cls[p] == (unsigned char)t) c++;
        s_cnt[t] = c;
    }
    __syncthreads();
    if (t == 0){
        int a = 0;
        for (int c = 0; c < NC; c++){ s_off[c] = a; a += s_cnt[c]; }
    }
    __syncthreads();
    if (t < NC){
        int o = s_off[t];
        for (int p = 0; p < PPB; p++) if (s_cls[p] == (unsigned char)t) s_perm[o++] = (short)p;
    }
    __syncthreads();
}

__global__ __launch_bounds__(384, 6)
void cls3_fused(const float* __restrict__ X,
                const float* __restrict__ w1_0, const float* __restrict__ b1_0,
                const float* __restrict__ w1_1, const float* __restrict__ b1_1,
                const float* __restrict__ w1_2, const float* __restrict__ b1_2,
                const float* __restrict__ w2_0, const float* __restrict__ b2_0,
                const float* __restrict__ w2_1, const float* __restrict__ b2_1,
                const float* __restrict__ w2_2, const float* __restrict__ b2_2,
                const float* __restrict__ w3_0, const float* __restrict__ b3_0,
                const float* __restrict__ w3_1, const float* __restrict__ b3_1,
                const float* __restrict__ w3_2, const float* __restrict__ b3_2,
                int* __restrict__ out)
{
    __shared__ float s_w0[4096];     // stage-1 w1_0[h]  [o=32][i=128]
    __shared__ float s_w1[1024];     // stage-1 w1_1[h]  [o=32][i=32]
    __shared__ float s_w2[256];      // stage-1 w1_2[h]  [o=8][i=32]
    __shared__ float s_A[PPB*33];    // stage-1 activations ping
    __shared__ float s_B[PPB*33];    // stage-1 activations pong
    __shared__ unsigned char s_cls[PPB];    // stage-1 routing (read-only during stage 2)
    __shared__ unsigned char s_cls2[PPB];   // stage-2 routing (written during stage 2)
    __shared__ short s_perm[PPB];
    __shared__ int   s_raw[PPB];
    __shared__ int   s_cnt[64];
    __shared__ int   s_off[64];

    const int h  = blockIdx.x >> 1;
    const int wb = (blockIdx.x & 1) * PPB;   // pixel-base within the line
    const int t  = threadIdx.x;
    const int l  = t & 63;                   // lane within wave
    const int gb = l & ~7;                   // 8-lane pixel-group base lane

    // ================= stage 1 (w=pixel 0..47, s=0..7 owns 4 channels) =================
    {
        const int w  = t % PPB;
        const int s  = t / PPB;
        const int hw = h*96 + wb + w;

        const float* g0 = w1_0 + (size_t)h*4096;
        for (int j = t; j < 4096; j += 384) s_w0[j] = g0[j];
        const float* g1 = w1_1 + (size_t)h*1024;
        for (int j = t; j < 1024; j += 384) s_w1[j] = g1[j];
        const float* g2 = w1_2 + (size_t)h*256;
        for (int j = t; j < 256; j += 384) s_w2[j] = g2[j];
        __syncthreads();

        // L0: 128 -> 32 (X from global, coalesced)
        {
            float acc[4];
            const float* bp = b1_0 + h*32 + s*4;
            #pragma unroll
            for (int k=0;k<4;k++) acc[k] = bp[k];
            #pragma unroll 4
            for (int i4=0;i4<32;i4++){
                const float x0 = X[(size_t)(4*i4+0)*HW_ + hw];
                const float x1 = X[(size_t)(4*i4+1)*HW_ + hw];
                const float x2 = X[(size_t)(4*i4+2)*HW_ + hw];
                const float x3 = X[(size_t)(4*i4+3)*HW_ + hw];
                #pragma unroll
                for (int k=0;k<4;k++){
                    const float4 q = *(const float4*)&s_w0[(s*4+k)*128 + 4*i4];
                    acc[k] += x0*q.x; acc[k] += x1*q.y; acc[k] += x2*q.z; acc[k] += x3*q.w;
                }
            }
            #pragma unroll
            for (int k=0;k<4;k++) s_A[w*33 + s*4 + k] = lrelu(acc[k]);
        }
        __syncthreads();

        // L1: 32 -> 32
        {
            float acc[4];
            const float* bp = b1_1 + h*32 + s*4;
            #pragma unroll
            for (int k=0;k<4;k++) acc[k] = bp[k];
            #pragma unroll
            for (int i4=0;i4<8;i4++){
                const float x0 = s_A[w*33 + 4*i4+0];
                const float x1 = s_A[w*33 + 4*i4+1];
                const float x2 = s_A[w*33 + 4*i4+2];
                const float x3 = s_A[w*33 + 4*i4+3];
                #pragma unroll
                for (int k=0;k<4;k++){
                    const float4 q = *(const float4*)&s_w1[(s*4+k)*32 + 4*i4];
                    acc[k] += x0*q.x; acc[k] += x1*q.y; acc[k] += x2*q.z; acc[k] += x3*q.w;
                }
            }
            #pragma unroll
            for (int k=0;k<4;k++) s_B[w*33 + s*4 + k] = lrelu(acc[k]);
        }
        __syncthreads();

        // L2: 32 -> 8 (each s owns 1 output)
        {
            float acc = b1_2[h*8 + s];
            #pragma unroll
            for (int i4=0;i4<8;i4++){
                const float4 q = *(const float4*)&s_w2[s*32 + 4*i4];
                acc += s_B[w*33 + 4*i4+0]*q.x;
                acc += s_B[w*33 + 4*i4+1]*q.y;
                acc += s_B[w*33 + 4*i4+2]*q.z;
                acc += s_B[w*33 + 4*i4+3]*q.w;
            }
            s_A[w*33 + s] = acc;
        }
        __syncthreads();

        if (s == 0){
            const float* sc = &s_A[w*33];
            float best = sc[0]; int bi = 0;
            #pragma unroll
            for (int k=1;k<8;k++){ const float v = sc[k]; if (v > best){ best = v; bi = k; } }
            s_cls[w] = (unsigned char)bi;
        }
        __syncthreads();
    }

    // sort pixels by stage-1 class (8 classes)
    sort_by_class<8>(s_cls, s_perm, s_cnt, s_off, t);

    // ================= stage 2 — BARRIER-FREE (activations live in 8-lane group) =================
    const int p = t >> 3;
    const int j = t & 7;
    {
        const int sp = s_perm[p];
        const int c  = s_cls[sp];          // s_cls is read-only during stage 2
        const long e = (long)h*8 + c;
        const int hw = h*96 + wb + sp;

        // L0: 128 -> 32 (8 lanes/pixel cover one 128B expert row)
        float4 acc = *(const float4*)&b2_0[e*32 + j*4];
        const float* W0 = w2_0 + e*4096 + j*4;
        #pragma unroll 8
        for (int i=0;i<128;i++){
            const float xv = X[(size_t)i*HW_ + hw];
            const float4 q = *(const float4*)&W0[i*32];
            acc.x += xv*q.x; acc.y += xv*q.y; acc.z += xv*q.z; acc.w += xv*q.w;
        }
        float a0[4] = { lrelu(acc.x), lrelu(acc.y), lrelu(acc.z), lrelu(acc.w) };

        // L1: 32 -> 32 (activation exchange via shfl within the 8-lane group)
        float4 ac2 = *(const float4*)&b2_1[e*32 + j*4];
        const float* W1 = w2_1 + e*1024 + j*4;
        #pragma unroll
        for (int i=0;i<32;i++){
            const float xv = __shfl(a0[i&3], gb + (i>>2), 64);
            const float4 q = *(const float4*)&W1[i*32];
            ac2.x += xv*q.x; ac2.y += xv*q.y; ac2.z += xv*q.z; ac2.w += xv*q.w;
        }
        float a1[4] = { lrelu(ac2.x), lrelu(ac2.y), lrelu(ac2.z), lrelu(ac2.w) };

        // L2: 32 -> 16 (each lane owns 2 channels)
        float2 sc = *(const float2*)&b2_2[e*16 + j*2];
        const float* W2 = w2_2 + e*512 + j*2;
        #pragma unroll
        for (int i=0;i<32;i++){
            const float xv = __shfl(a1[i&3], gb + (i>>2), 64);
            const float2 r = *(const float2*)&W2[i*16];
            sc.x += xv*r.x; sc.y += xv*r.y;
        }
        float best = sc.x; int bi = j*2;
        if (sc.y > best){ best = sc.y; bi = j*2+1; }
        #pragma unroll
        for (int off=1; off<8; off<<=1){
            const float ob = __shfl_xor(best, off, 64);
            const int  obi = __shfl_xor(bi,  off, 64);
            if (ob > best || (ob == best && obi < bi)){ best = ob; bi = obi; }
        }
        if (j == 0){
            const int raw = c*8 + bi - 4;
            s_raw[sp]  = raw;
            s_cls2[sp] = (unsigned char)(raw < 0 ? 0 : (raw > 63 ? 63 : raw));
        }
    }
    __syncthreads();   // all stage-2 writes visible; s_perm free for re-sort

    // sort pixels by clipped inds12 (64 classes)
    sort_by_class<64>(s_cls2, s_perm, s_cnt, s_off, t);

    // ================= stage 3 — BARRIER-FREE =================
    {
        const int sp = s_perm[p];
        const int c  = s_cls2[sp];
        const long e = (long)h*64 + c;
        const int hw = h*96 + wb + sp;

        float4 acc = *(const float4*)&b3_0[e*32 + j*4];
        const float* W0 = w3_0 + e*4096 + j*4;
        #pragma unroll 8
        for (int i=0;i<128;i++){
            const float xv = X[(size_t)i*HW_ + hw];
            const float4 q = *(const float4*)&W0[i*32];
            acc.x += xv*q.x; acc.y += xv*q.y; acc.z += xv*q.z; acc.w += xv*q.w;
        }
        float a0[4] = { lrelu(acc.x), lrelu(acc.y), lrelu(acc.z), lrelu(acc.w) };

        float4 ac2 = *(const float4*)&b3_1[e*32 + j*4];
        const float* W1 = w3_1 + e*1024 + j*4;
        #pragma unroll
        for (int i=0;i<32;i++){
            const float xv = __shfl(a0[i&3], gb + (i>>2), 64);
            const float4 q = *(const float4*)&W1[i*32];
            ac2.x += xv*q.x; ac2.y += xv*q.y; ac2.z += xv*q.z; ac2.w += xv*q.w;
        }
        float a1[4] = { lrelu(ac2.x), lrelu(ac2.y), lrelu(ac2.z), lrelu(ac2.w) };

        float2 sc = *(const float2*)&b3_2[e*16 + j*2];
        const float* W2 = w3_2 + e*512 + j*2;
        #pragma unroll
        for (int i=0;i<32;i++){
            const float xv = __shfl(a1[i&3], gb + (i>>2), 64);
            const float2 r = *(const float2*)&W2[i*16];
            sc.x += xv*r.x; sc.y += xv*r.y;
        }
        float best = sc.x; int bi = j*2;
        if (sc.y > best){ best = sc.y; bi = j*2+1; }
        #pragma unroll
        for (int off=1; off<8; off<<=1){
            const float ob = __shfl_xor(best, off, 64);
            const int  obi = __shfl_xor(bi,  off, 64);
            if (ob > best || (ob == best && obi < bi)){ best = ob; bi = obi; }
        }
        if (j == 0){
            int v = s_raw[sp]*8 + bi - 4;
            v = v < 0 ? 0 : (v > 511 ? 511 : v);
            out[h*96 + wb + sp] = v;
        }
    }
}

extern "C" void kernel_launch(void* const* d_in, const int* in_sizes, int n_in,
                              void* d_out, int out_size, void* d_ws, size_t ws_size,
                              hipStream_t stream) {
    const float* X    = (const float*)d_in[0];
    const float* w1_0 = (const float*)d_in[1];
    const float* b1_0 = (const float*)d_in[2];
    const float* w1_1 = (const float*)d_in[3];
    const float* b1_1 = (const float*)d_in[4];
    const float* w1_2 = (const float*)d_in[5];
    const float* b1_2 = (const float*)d_in[6];
    const float* w2_0 = (const float*)d_in[7];
    const float* b2_0 = (const float*)d_in[8];
    const float* w2_1 = (const float*)d_in[9];
    const float* b2_1 = (const float*)d_in[10];
    const float* w2_2 = (const float*)d_in[11];
    const float* b2_2 = (const float*)d_in[12];
    const float* w3_0 = (const float*)d_in[13];
    const float* b3_0 = (const float*)d_in[14];
    const float* w3_1 = (const float*)d_in[15];
    const float* b3_1 = (const float*)d_in[16];
    const float* w3_2 = (const float*)d_in[17];
    const float* b3_2 = (const float*)d_in[18];
    int* out = (int*)d_out;

    cls3_fused<<<H_*2, 384, 0, stream>>>(X,
        w1_0, b1_0, w1_1, b1_1, w1_2, b1_2,
        w2_0, b2_0, w2_1, b2_1, w2_2, b2_2,
        w3_0, b3_0, w3_1, b3_1, w3_2, b3_2,
        out);
}